// Round 1
// baseline (428.372 us; speedup 1.0000x reference)
//
#include <hip/hip_runtime.h>

#define NP 64
#define HID 1024
#define DIN 16
#define BATCH 2048
#define DTOT 18433
#define OFF_B1 16384
#define OFF_W2 17408
#define OFF_B2 18432
#define STEPC 0.0015625f  /* 0.1/64 */
#define GCH 128
#define NGBLK 145  /* ceil(18433/128) */

__device__ __forceinline__ float theta_at(int i, int d,
    const float* __restrict__ W1, const float* __restrict__ b1,
    const float* __restrict__ W2, const float* __restrict__ b2) {
  if (d < OFF_B1) return W1[i * 16384 + d];
  if (d < OFF_W2) return b1[i * HID + (d - OFF_B1)];
  if (d < OFF_B2) return W2[i * HID + (d - OFF_W2)];
  return b2[i];
}

// K1: forward pass -> e[n,b] = y[b] - yhat[n,b].  grid(64,8) x 256, thread<->b
__global__ __launch_bounds__(256) void k_forward(
    const float* __restrict__ W1, const float* __restrict__ b1,
    const float* __restrict__ W2, const float* __restrict__ b2,
    const float* __restrict__ X, const float* __restrict__ y,
    float* __restrict__ e) {
  const int n = blockIdx.x;
  const int b = blockIdx.y * 256 + threadIdx.x;
  __shared__ float4 w1s[256];  // 64 k-rows x 16 d
  __shared__ float b1s[64];
  __shared__ float w2s[64];
  const float4* __restrict__ Xv = (const float4*)X + b * 4;
  const float4 x0 = Xv[0], x1 = Xv[1], x2 = Xv[2], x3 = Xv[3];
  const float4* __restrict__ W1v = (const float4*)W1 + n * 4096;
  float acc = 0.f;
  for (int kt = 0; kt < HID; kt += 64) {
    __syncthreads();
    w1s[threadIdx.x] = W1v[kt * 4 + threadIdx.x];
    if (threadIdx.x < 64) b1s[threadIdx.x] = b1[n * HID + kt + threadIdx.x];
    else if (threadIdx.x < 128) w2s[threadIdx.x - 64] = W2[n * HID + kt + (threadIdx.x - 64)];
    __syncthreads();
    #pragma unroll 4
    for (int kk = 0; kk < 64; ++kk) {
      const float4 w0 = w1s[kk * 4 + 0], w1 = w1s[kk * 4 + 1];
      const float4 w2 = w1s[kk * 4 + 2], w3 = w1s[kk * 4 + 3];
      float p0 = fmaf(w0.x, x0.x, fmaf(w0.y, x0.y, fmaf(w0.z, x0.z, w0.w * x0.w)));
      float p1 = fmaf(w1.x, x1.x, fmaf(w1.y, x1.y, fmaf(w1.z, x1.z, w1.w * x1.w)));
      float p2 = fmaf(w2.x, x2.x, fmaf(w2.y, x2.y, fmaf(w2.z, x2.z, w2.w * x2.w)));
      float p3 = fmaf(w3.x, x3.x, fmaf(w3.y, x3.y, fmaf(w3.z, x3.z, w3.w * x3.w)));
      float pre = b1s[kk] + ((p0 + p1) + (p2 + p3));
      acc = fmaf(w2s[kk], fmaxf(pre, 0.f), acc);
    }
  }
  e[n * BATCH + b] = y[b] - (acc + b2[n]);
}

// K1b: V[n, 18432] = sum_b e - 2*b2.  grid(64) x 256
__global__ __launch_bounds__(256) void k_gb2(
    const float* __restrict__ e, const float* __restrict__ b2,
    float* __restrict__ vout) {
  const int n = blockIdx.x;
  __shared__ float red[256];
  float a = 0.f;
  for (int i = threadIdx.x; i < BATCH; i += 256) a += e[n * BATCH + i];
  red[threadIdx.x] = a;
  __syncthreads();
  for (int off = 128; off > 0; off >>= 1) {
    if (threadIdx.x < off) red[threadIdx.x] += red[threadIdx.x + off];
    __syncthreads();
  }
  if (threadIdx.x == 0) vout[(size_t)n * DTOT + OFF_B2] = red[0] - 2.f * b2[n];
}

// K2: backward, writes V = grad_ll - 2*theta for W1/b1/W2 rows. grid(64,4) x 256, thread<->k
__global__ __launch_bounds__(256) void k_backward(
    const float* __restrict__ W1, const float* __restrict__ b1,
    const float* __restrict__ W2, const float* __restrict__ X,
    const float* __restrict__ e, float* __restrict__ vout) {
  const int n = blockIdx.x;
  const int k = blockIdx.y * 256 + threadIdx.x;
  __shared__ float4 xs[2048];  // 512 b-rows x 16 d
  __shared__ float es[512];
  const float4* __restrict__ W1v = (const float4*)W1 + (n * HID + k) * 4;
  const float4 w0 = W1v[0], w1 = W1v[1], w2 = W1v[2], w3 = W1v[3];
  const float b1r = b1[n * HID + k];
  const float w2r = W2[n * HID + k];
  float4 a0 = {0, 0, 0, 0}, a1 = {0, 0, 0, 0}, a2 = {0, 0, 0, 0}, a3 = {0, 0, 0, 0};
  float gb1 = 0.f, gw2 = 0.f;
  const float4* __restrict__ Xv = (const float4*)X;
  for (int bt = 0; bt < 4; ++bt) {
    __syncthreads();
    for (int idx = threadIdx.x; idx < 2048; idx += 256) xs[idx] = Xv[bt * 2048 + idx];
    for (int idx = threadIdx.x; idx < 512; idx += 256) es[idx] = e[n * BATCH + bt * 512 + idx];
    __syncthreads();
    #pragma unroll 2
    for (int bb = 0; bb < 512; ++bb) {
      const float4 x0 = xs[bb * 4 + 0], x1 = xs[bb * 4 + 1];
      const float4 x2 = xs[bb * 4 + 2], x3 = xs[bb * 4 + 3];
      const float eb = es[bb];
      float p0 = fmaf(w0.x, x0.x, fmaf(w0.y, x0.y, fmaf(w0.z, x0.z, w0.w * x0.w)));
      float p1 = fmaf(w1.x, x1.x, fmaf(w1.y, x1.y, fmaf(w1.z, x1.z, w1.w * x1.w)));
      float p2 = fmaf(w2.x, x2.x, fmaf(w2.y, x2.y, fmaf(w2.z, x2.z, w2.w * x2.w)));
      float p3 = fmaf(w3.x, x3.x, fmaf(w3.y, x3.y, fmaf(w3.z, x3.z, w3.w * x3.w)));
      const float pre = b1r + ((p0 + p1) + (p2 + p3));
      gw2 = fmaf(eb, fmaxf(pre, 0.f), gw2);
      const float g = (pre > 0.f) ? eb * w2r : 0.f;
      gb1 += g;
      a0.x = fmaf(g, x0.x, a0.x); a0.y = fmaf(g, x0.y, a0.y);
      a0.z = fmaf(g, x0.z, a0.z); a0.w = fmaf(g, x0.w, a0.w);
      a1.x = fmaf(g, x1.x, a1.x); a1.y = fmaf(g, x1.y, a1.y);
      a1.z = fmaf(g, x1.z, a1.z); a1.w = fmaf(g, x1.w, a1.w);
      a2.x = fmaf(g, x2.x, a2.x); a2.y = fmaf(g, x2.y, a2.y);
      a2.z = fmaf(g, x2.z, a2.z); a2.w = fmaf(g, x2.w, a2.w);
      a3.x = fmaf(g, x3.x, a3.x); a3.y = fmaf(g, x3.y, a3.y);
      a3.z = fmaf(g, x3.z, a3.z); a3.w = fmaf(g, x3.w, a3.w);
    }
  }
  float* __restrict__ vr = vout + (size_t)n * DTOT + k * 16;
  vr[0]  = a0.x - 2.f * w0.x; vr[1]  = a0.y - 2.f * w0.y;
  vr[2]  = a0.z - 2.f * w0.z; vr[3]  = a0.w - 2.f * w0.w;
  vr[4]  = a1.x - 2.f * w1.x; vr[5]  = a1.y - 2.f * w1.y;
  vr[6]  = a1.z - 2.f * w1.z; vr[7]  = a1.w - 2.f * w1.w;
  vr[8]  = a2.x - 2.f * w2.x; vr[9]  = a2.y - 2.f * w2.y;
  vr[10] = a2.z - 2.f * w2.z; vr[11] = a2.w - 2.f * w2.w;
  vr[12] = a3.x - 2.f * w3.x; vr[13] = a3.y - 2.f * w3.y;
  vr[14] = a3.z - 2.f * w3.z; vr[15] = a3.w - 2.f * w3.w;
  vout[(size_t)n * DTOT + OFF_B1 + k] = gb1 - 2.f * b1r;
  vout[(size_t)n * DTOT + OFF_W2 + k] = gw2 - 2.f * w2r;
}

// K3: Gram partials per 128-column chunk. grid(145) x 256
__global__ __launch_bounds__(256) void k_gram_partial(
    const float* __restrict__ W1, const float* __restrict__ b1,
    const float* __restrict__ W2, const float* __restrict__ b2,
    float* __restrict__ gpart) {
  __shared__ float ths[64 * 129];
  const int c0 = blockIdx.x * GCH;
  const int cols = min(GCH, DTOT - c0);
  for (int idx = threadIdx.x; idx < 64 * GCH; idx += 256) {
    const int i = idx >> 7, dd = idx & 127;
    ths[i * 129 + dd] = (dd < cols) ? theta_at(i, c0 + dd, W1, b1, W2, b2) : 0.f;
  }
  __syncthreads();
  const int i0 = (threadIdx.x >> 4) << 2;
  const int j0 = (threadIdx.x & 15) << 2;
  float acc[4][4] = {};
  for (int dc = 0; dc < cols; ++dc) {
    const float ai0 = ths[(i0 + 0) * 129 + dc], ai1 = ths[(i0 + 1) * 129 + dc];
    const float ai2 = ths[(i0 + 2) * 129 + dc], ai3 = ths[(i0 + 3) * 129 + dc];
    const float bj0 = ths[(j0 + 0) * 129 + dc], bj1 = ths[(j0 + 1) * 129 + dc];
    const float bj2 = ths[(j0 + 2) * 129 + dc], bj3 = ths[(j0 + 3) * 129 + dc];
    acc[0][0] = fmaf(ai0, bj0, acc[0][0]); acc[0][1] = fmaf(ai0, bj1, acc[0][1]);
    acc[0][2] = fmaf(ai0, bj2, acc[0][2]); acc[0][3] = fmaf(ai0, bj3, acc[0][3]);
    acc[1][0] = fmaf(ai1, bj0, acc[1][0]); acc[1][1] = fmaf(ai1, bj1, acc[1][1]);
    acc[1][2] = fmaf(ai1, bj2, acc[1][2]); acc[1][3] = fmaf(ai1, bj3, acc[1][3]);
    acc[2][0] = fmaf(ai2, bj0, acc[2][0]); acc[2][1] = fmaf(ai2, bj1, acc[2][1]);
    acc[2][2] = fmaf(ai2, bj2, acc[2][2]); acc[2][3] = fmaf(ai2, bj3, acc[2][3]);
    acc[3][0] = fmaf(ai3, bj0, acc[3][0]); acc[3][1] = fmaf(ai3, bj1, acc[3][1]);
    acc[3][2] = fmaf(ai3, bj2, acc[3][2]); acc[3][3] = fmaf(ai3, bj3, acc[3][3]);
  }
  float* __restrict__ gp = gpart + blockIdx.x * 4096;
  #pragma unroll
  for (int a = 0; a < 4; ++a)
    #pragma unroll
    for (int bj = 0; bj < 4; ++bj)
      gp[(i0 + a) * 64 + j0 + bj] = acc[a][bj];
}

// K4a: reduce Gram partials. grid(16) x 256
__global__ __launch_bounds__(256) void k_gram_reduce(
    const float* __restrict__ gpart, float* __restrict__ gram) {
  const int pair = blockIdx.x * 256 + threadIdx.x;
  float a = 0.f;
  for (int p = 0; p < NGBLK; ++p) a += gpart[p * 4096 + pair];
  gram[pair] = a;
}

// K4b: kd = exp(-d2/2), s = row sums. grid(1) x 256
__global__ __launch_bounds__(256) void k_kd(
    const float* __restrict__ gram, float* __restrict__ kd, float* __restrict__ s) {
  __shared__ float kds[4096];
  __shared__ float sq[64];
  if (threadIdx.x < 64) sq[threadIdx.x] = gram[threadIdx.x * 65];
  __syncthreads();
  for (int q = threadIdx.x; q < 4096; q += 256) {
    const int i = q >> 6, j = q & 63;
    const float d2 = fmaxf(sq[i] + sq[j] - 2.f * gram[q], 0.f);
    const float kv = expf(-0.5f * d2);
    kds[q] = kv;
    kd[q] = kv;
  }
  __syncthreads();
  if (threadIdx.x < 64) {
    float a = 0.f;
    for (int j = 0; j < 64; ++j) a += kds[threadIdx.x * 64 + j];
    s[threadIdx.x] = a;
  }
}

// K5: out[i,d] = theta[i,d]*(1+c*s[i]) + c*sum_j kd[i,j]*V[j,d]; V staged from d_out
// before overwrite. grid(145) x 256
__global__ __launch_bounds__(256) void k_update(
    const float* __restrict__ W1, const float* __restrict__ b1,
    const float* __restrict__ W2, const float* __restrict__ b2,
    const float* __restrict__ kd, const float* __restrict__ s,
    float* __restrict__ vout) {
  __shared__ float Vs[64 * 129];
  __shared__ float kds[4096];
  __shared__ float ss[64];
  const int c0 = blockIdx.x * GCH;
  const int cols = min(GCH, DTOT - c0);
  for (int idx = threadIdx.x; idx < 64 * GCH; idx += 256) {
    const int i = idx >> 7, dd = idx & 127;
    Vs[i * 129 + dd] = (dd < cols) ? vout[(size_t)i * DTOT + c0 + dd] : 0.f;
  }
  for (int q = threadIdx.x; q < 4096; q += 256) kds[q] = kd[q];
  if (threadIdx.x < 64) ss[threadIdx.x] = s[threadIdx.x];
  __syncthreads();
  const int col = threadIdx.x & 127;
  const int ihalf = threadIdx.x >> 7;
  if (col < cols) {
    const int d = c0 + col;
    float acc[32] = {};
    for (int j = 0; j < 64; ++j) {
      const float v = Vs[j * 129 + col];
      #pragma unroll
      for (int a = 0; a < 32; ++a)
        acc[a] = fmaf(kds[(ihalf * 32 + a) * 64 + j], v, acc[a]);
    }
    #pragma unroll
    for (int a = 0; a < 32; ++a) {
      const int i = ihalf * 32 + a;
      const float th = theta_at(i, d, W1, b1, W2, b2);
      vout[(size_t)i * DTOT + d] = th * (1.f + STEPC * ss[i]) + STEPC * acc[a];
    }
  }
}

extern "C" void kernel_launch(void* const* d_in, const int* in_sizes, int n_in,
                              void* d_out, int out_size, void* d_ws, size_t ws_size,
                              hipStream_t stream) {
  const float* W1 = (const float*)d_in[0];
  const float* b1 = (const float*)d_in[1];
  const float* W2 = (const float*)d_in[2];
  const float* b2 = (const float*)d_in[3];
  const float* X  = (const float*)d_in[4];
  const float* y  = (const float*)d_in[5];
  float* vout = (float*)d_out;

  float* e     = (float*)d_ws;            // 64*2048
  float* gpart = e + NP * BATCH;          // 145*4096
  float* gram  = gpart + NGBLK * 4096;    // 4096
  float* kd    = gram + 4096;             // 4096
  float* s     = kd + 4096;               // 64

  k_forward<<<dim3(NP, 8), 256, 0, stream>>>(W1, b1, W2, b2, X, y, e);
  k_gb2<<<NP, 256, 0, stream>>>(e, b2, vout);
  k_backward<<<dim3(NP, 4), 256, 0, stream>>>(W1, b1, W2, X, e, vout);
  k_gram_partial<<<NGBLK, 256, 0, stream>>>(W1, b1, W2, b2, gpart);
  k_gram_reduce<<<16, 256, 0, stream>>>(gpart, gram);
  k_kd<<<1, 256, 0, stream>>>(gram, kd, s);
  k_update<<<NGBLK, 256, 0, stream>>>(W1, b1, W2, b2, kd, s, vout);
}

// Round 2
// 173.561 us; speedup vs baseline: 2.4681x; 2.4681x over previous
//
#include <hip/hip_runtime.h>

#define NP 64
#define HID 1024
#define DIN 16
#define BATCH 2048
#define DTOT 18433
#define OFF_B1 16384
#define OFF_W2 17408
#define OFF_B2 18432
#define STEPC 0.0015625f  /* 0.1/64 */
#define GCH 128
#define NGBLK 145  /* ceil(18433/128) */

typedef __attribute__((ext_vector_type(8))) short bf16x8;
typedef __attribute__((ext_vector_type(4))) short short4v;
typedef __attribute__((ext_vector_type(4))) float f32x4;

__device__ __forceinline__ short f2bf(float f) {
  union { float f; unsigned u; } v; v.f = f;
  unsigned r = v.u + 0x7FFFu + ((v.u >> 16) & 1u);
  return (short)(r >> 16);
}

// Load an A-operand fragment of a row-major [rows][16] fp32 matrix, zero-padded
// K 16->32. Layout: A[row=lane&15][k=(lane>>4)*8+j].
__device__ __forceinline__ bf16x8 load_row_frag(const float* __restrict__ M,
                                                int row, int lhi) {
  bf16x8 a;
  if (lhi < 2) {
    const float* p = M + (size_t)row * DIN + lhi * 8;
    f32x4 q0 = *(const f32x4*)p;
    f32x4 q1 = *(const f32x4*)(p + 4);
    a[0] = f2bf(q0[0]); a[1] = f2bf(q0[1]); a[2] = f2bf(q0[2]); a[3] = f2bf(q0[3]);
    a[4] = f2bf(q1[0]); a[5] = f2bf(q1[1]); a[6] = f2bf(q1[2]); a[7] = f2bf(q1[3]);
  } else {
    a = (bf16x8){0, 0, 0, 0, 0, 0, 0, 0};
  }
  return a;
}

__device__ __forceinline__ float theta_at(int i, int d,
    const float* __restrict__ W1, const float* __restrict__ b1,
    const float* __restrict__ W2, const float* __restrict__ b2) {
  if (d < OFF_B1) return W1[i * 16384 + d];
  if (d < OFF_W2) return b1[i * HID + (d - OFF_B1)];
  if (d < OFF_B2) return W2[i * HID + (d - OFF_W2)];
  return b2[i];
}

// K1: MFMA forward. grid(64 n, 8 bg) x 512. Each wave owns 8 k-tiles; per
// 32-row b-tile: pre = X@W1^T (16x16x32, K padded), yhat reduced via LDS.
__global__ __launch_bounds__(512) void k_fwd(
    const float* __restrict__ W1, const float* __restrict__ b1,
    const float* __restrict__ W2, const float* __restrict__ b2,
    const float* __restrict__ X, const float* __restrict__ y,
    float* __restrict__ e_ws, float* __restrict__ Pb2) {
  const int n = blockIdx.x, bg = blockIdx.y;
  const int tid = threadIdx.x;
  const int w = tid >> 6, l = tid & 63;
  const int lrow = l & 15, lhi = l >> 4;
  __shared__ float yhp[8][32];

  bf16x8 b1f[8];
  float b1r[8], w2r[8];
  #pragma unroll
  for (int ktl = 0; ktl < 8; ++ktl) {
    const int k = (w * 8 + ktl) * 16 + lrow;
    b1f[ktl] = load_row_frag(W1, n * HID + k, lhi);
    b1r[ktl] = b1[n * HID + k];
    w2r[ktl] = W2[n * HID + k];
  }
  const float b2n = b2[n];
  float gb2p = 0.f;

  for (int bt = 0; bt < 8; ++bt) {
    const int bbase = bg * 256 + bt * 32;
    float yh[2][4] = {};
    #pragma unroll
    for (int rt = 0; rt < 2; ++rt) {
      bf16x8 a1 = load_row_frag(X, bbase + rt * 16 + lrow, lhi);
      #pragma unroll
      for (int ktl = 0; ktl < 8; ++ktl) {
        f32x4 c = {0.f, 0.f, 0.f, 0.f};
        c = __builtin_amdgcn_mfma_f32_16x16x32_bf16(a1, b1f[ktl], c, 0, 0, 0);
        #pragma unroll
        for (int r = 0; r < 4; ++r) {
          const float pre = c[r] + b1r[ktl];
          yh[rt][r] = fmaf(fmaxf(pre, 0.f), w2r[ktl], yh[rt][r]);
        }
      }
    }
    // reduce over the 16 lanes sharing lhi (they cover k via lrow)
    #pragma unroll
    for (int off = 1; off < 16; off <<= 1)
      #pragma unroll
      for (int rt = 0; rt < 2; ++rt)
        #pragma unroll
        for (int r = 0; r < 4; ++r)
          yh[rt][r] += __shfl_xor(yh[rt][r], off);
    if (lrow == 0) {
      #pragma unroll
      for (int rt = 0; rt < 2; ++rt)
        #pragma unroll
        for (int r = 0; r < 4; ++r)
          yhp[w][rt * 16 + lhi * 4 + r] = yh[rt][r];
    }
    __syncthreads();
    if (tid < 32) {
      float s = 0.f;
      #pragma unroll
      for (int q = 0; q < 8; ++q) s += yhp[q][tid];
      const int b = bbase + tid;
      const float ev = y[b] - (s + b2n);
      e_ws[n * BATCH + b] = ev;
      gb2p += ev;
    }
    __syncthreads();
  }
  if (tid < 32) {
    #pragma unroll
    for (int off = 1; off < 32; off <<= 1) gb2p += __shfl_xor(gb2p, off);
    if (tid == 0) Pb2[n * 8 + bg] = gb2p;
  }
}

// K2: MFMA backward. grid(64 n, 8 kg) x 512. Each wave owns one 16-row k-tile
// of its block's 128 k-rows. Per 32-b-tile: recompute pre via MFMA, form
// G = e*w2*mask (bf16) into XOR-swizzled LDS, then dW1 += G^T @ X via MFMA.
__global__ __launch_bounds__(512) void k_bwd(
    const float* __restrict__ W1, const float* __restrict__ b1,
    const float* __restrict__ W2, const float* __restrict__ b2,
    const float* __restrict__ X, const float* __restrict__ e_ws,
    const float* __restrict__ Pb2, float* __restrict__ vout) {
  const int n = blockIdx.x, kg = blockIdx.y;
  const int tid = threadIdx.x;
  const int w = tid >> 6, l = tid & 63;
  const int lrow = l & 15, lhi = l >> 4;
  __shared__ short Xt[16 * 2048];  // X^T bf16, swizzled: idx = d*2048+b ^ ((d&7)<<3)
  __shared__ short Gt[128 * 32];   // G^T bf16, swizzled: idx = kl*32+b ^ ((kl&7)<<3)

  // stage X^T (each thread converts 4 b-rows)
  {
    const int b0 = tid * 4;
    float rows[4][16];
    #pragma unroll
    for (int i = 0; i < 4; ++i) {
      const f32x4* p = (const f32x4*)&X[(b0 + i) * DIN];
      f32x4 q0 = p[0], q1 = p[1], q2 = p[2], q3 = p[3];
      rows[i][0] = q0[0]; rows[i][1] = q0[1]; rows[i][2] = q0[2]; rows[i][3] = q0[3];
      rows[i][4] = q1[0]; rows[i][5] = q1[1]; rows[i][6] = q1[2]; rows[i][7] = q1[3];
      rows[i][8] = q2[0]; rows[i][9] = q2[1]; rows[i][10] = q2[2]; rows[i][11] = q2[3];
      rows[i][12] = q3[0]; rows[i][13] = q3[1]; rows[i][14] = q3[2]; rows[i][15] = q3[3];
    }
    #pragma unroll
    for (int d = 0; d < 16; ++d) {
      short4v s4;
      s4[0] = f2bf(rows[0][d]); s4[1] = f2bf(rows[1][d]);
      s4[2] = f2bf(rows[2][d]); s4[3] = f2bf(rows[3][d]);
      *(short4v*)&Xt[(d * 2048 + b0) ^ ((d & 7) << 3)] = s4;
    }
  }

  const int kt_g = kg * 8 + w;            // this wave's global k-tile
  const int kglob = kt_g * 16 + lrow;     // k row this lane loads W1 for
  const int klocal = w * 16 + lrow;       // row in Gt
  bf16x8 b1f = load_row_frag(W1, n * HID + kglob, lhi);
  const float b1r = b1[n * HID + kglob];
  const float w2r = W2[n * HID + kglob];
  f32x4 c2 = {0.f, 0.f, 0.f, 0.f};
  float gw2a = 0.f, gb1a = 0.f;
  __syncthreads();

  for (int bt = 0; bt < 64; ++bt) {
    #pragma unroll
    for (int rt = 0; rt < 2; ++rt) {
      bf16x8 a1 = load_row_frag(X, bt * 32 + rt * 16 + lrow, lhi);
      f32x4 c1 = {0.f, 0.f, 0.f, 0.f};
      c1 = __builtin_amdgcn_mfma_f32_16x16x32_bf16(a1, b1f, c1, 0, 0, 0);
      f32x4 ef = *(const f32x4*)&e_ws[n * BATCH + bt * 32 + rt * 16 + lhi * 4];
      short4v g4;
      #pragma unroll
      for (int r = 0; r < 4; ++r) {
        const float pre = c1[r] + b1r;
        gw2a = fmaf(ef[r], fmaxf(pre, 0.f), gw2a);
        const float g = (pre > 0.f) ? ef[r] * w2r : 0.f;
        gb1a += g;
        g4[r] = f2bf(g);
      }
      *(short4v*)&Gt[(klocal * 32 + rt * 16 + lhi * 4) ^ ((klocal & 7) << 3)] = g4;
    }
    __syncthreads();
    const bf16x8 b2f = *(const bf16x8*)&Xt[(lrow * 2048 + bt * 32 + lhi * 8) ^ ((lrow & 7) << 3)];
    const bf16x8 a2f = *(const bf16x8*)&Gt[(klocal * 32 + lhi * 8) ^ ((klocal & 7) << 3)];
    c2 = __builtin_amdgcn_mfma_f32_16x16x32_bf16(a2f, b2f, c2, 0, 0, 0);
    __syncthreads();
  }

  // cross-lhi reduce for gb1/gw2 (lanes l, l^16, l^32, l^48 share lrow)
  gw2a += __shfl_xor(gw2a, 16); gw2a += __shfl_xor(gw2a, 32);
  gb1a += __shfl_xor(gb1a, 16); gb1a += __shfl_xor(gb1a, 32);

  // dW1 rows: C2 row = lhi*4+r (k within tile), col = lrow (d)
  #pragma unroll
  for (int r = 0; r < 4; ++r) {
    const int k = kt_g * 16 + lhi * 4 + r;
    vout[(size_t)n * DTOT + (size_t)k * 16 + lrow] =
        c2[r] - 2.f * W1[(n * HID + k) * DIN + lrow];
  }
  if (l < 16) {
    const int k = kt_g * 16 + l;
    vout[(size_t)n * DTOT + OFF_B1 + k] = gb1a - 2.f * b1[n * HID + k];
    vout[(size_t)n * DTOT + OFF_W2 + k] = gw2a - 2.f * W2[n * HID + k];
  }
  if (kg == 0 && tid == 0) {
    float sb = 0.f;
    #pragma unroll
    for (int q = 0; q < 8; ++q) sb += Pb2[n * 8 + q];
    vout[(size_t)n * DTOT + OFF_B2] = sb - 2.f * b2[n];
  }
}

// K3: Gram partials per 128-column chunk. grid(145) x 256
__global__ __launch_bounds__(256) void k_gram_partial(
    const float* __restrict__ W1, const float* __restrict__ b1,
    const float* __restrict__ W2, const float* __restrict__ b2,
    float* __restrict__ gpart) {
  __shared__ float ths[64 * 129];
  const int c0 = blockIdx.x * GCH;
  const int cols = min(GCH, DTOT - c0);
  for (int idx = threadIdx.x; idx < 64 * GCH; idx += 256) {
    const int i = idx >> 7, dd = idx & 127;
    ths[i * 129 + dd] = (dd < cols) ? theta_at(i, c0 + dd, W1, b1, W2, b2) : 0.f;
  }
  __syncthreads();
  const int i0 = (threadIdx.x >> 4) << 2;
  const int j0 = (threadIdx.x & 15) << 2;
  float acc[4][4] = {};
  for (int dc = 0; dc < cols; ++dc) {
    const float ai0 = ths[(i0 + 0) * 129 + dc], ai1 = ths[(i0 + 1) * 129 + dc];
    const float ai2 = ths[(i0 + 2) * 129 + dc], ai3 = ths[(i0 + 3) * 129 + dc];
    const float bj0 = ths[(j0 + 0) * 129 + dc], bj1 = ths[(j0 + 1) * 129 + dc];
    const float bj2 = ths[(j0 + 2) * 129 + dc], bj3 = ths[(j0 + 3) * 129 + dc];
    acc[0][0] = fmaf(ai0, bj0, acc[0][0]); acc[0][1] = fmaf(ai0, bj1, acc[0][1]);
    acc[0][2] = fmaf(ai0, bj2, acc[0][2]); acc[0][3] = fmaf(ai0, bj3, acc[0][3]);
    acc[1][0] = fmaf(ai1, bj0, acc[1][0]); acc[1][1] = fmaf(ai1, bj1, acc[1][1]);
    acc[1][2] = fmaf(ai1, bj2, acc[1][2]); acc[1][3] = fmaf(ai1, bj3, acc[1][3]);
    acc[2][0] = fmaf(ai2, bj0, acc[2][0]); acc[2][1] = fmaf(ai2, bj1, acc[2][1]);
    acc[2][2] = fmaf(ai2, bj2, acc[2][2]); acc[2][3] = fmaf(ai2, bj3, acc[2][3]);
    acc[3][0] = fmaf(ai3, bj0, acc[3][0]); acc[3][1] = fmaf(ai3, bj1, acc[3][1]);
    acc[3][2] = fmaf(ai3, bj2, acc[3][2]); acc[3][3] = fmaf(ai3, bj3, acc[3][3]);
  }
  float* __restrict__ gp = gpart + blockIdx.x * 4096;
  #pragma unroll
  for (int a = 0; a < 4; ++a)
    #pragma unroll
    for (int bj = 0; bj < 4; ++bj)
      gp[(i0 + a) * 64 + j0 + bj] = acc[a][bj];
}

// K4a: reduce Gram partials. grid(16) x 256
__global__ __launch_bounds__(256) void k_gram_reduce(
    const float* __restrict__ gpart, float* __restrict__ gram) {
  const int pair = blockIdx.x * 256 + threadIdx.x;
  float a = 0.f;
  for (int p = 0; p < NGBLK; ++p) a += gpart[p * 4096 + pair];
  gram[pair] = a;
}

// K4b: kd = exp(-d2/2), s = row sums. grid(1) x 256
__global__ __launch_bounds__(256) void k_kd(
    const float* __restrict__ gram, float* __restrict__ kd, float* __restrict__ s) {
  __shared__ float kds[4096];
  __shared__ float sq[64];
  if (threadIdx.x < 64) sq[threadIdx.x] = gram[threadIdx.x * 65];
  __syncthreads();
  for (int q = threadIdx.x; q < 4096; q += 256) {
    const int i = q >> 6, j = q & 63;
    const float d2 = fmaxf(sq[i] + sq[j] - 2.f * gram[q], 0.f);
    const float kv = expf(-0.5f * d2);
    kds[q] = kv;
    kd[q] = kv;
  }
  __syncthreads();
  if (threadIdx.x < 64) {
    float a = 0.f;
    for (int j = 0; j < 64; ++j) a += kds[threadIdx.x * 64 + j];
    s[threadIdx.x] = a;
  }
}

// K5: out[i,d] = theta[i,d]*(1+c*s[i]) + c*sum_j kd[i,j]*V[j,d]; V staged from
// d_out before overwrite. grid(145) x 256
__global__ __launch_bounds__(256) void k_update(
    const float* __restrict__ W1, const float* __restrict__ b1,
    const float* __restrict__ W2, const float* __restrict__ b2,
    const float* __restrict__ kd, const float* __restrict__ s,
    float* __restrict__ vout) {
  __shared__ float Vs[64 * 129];
  __shared__ float kds[4096];
  __shared__ float ss[64];
  const int c0 = blockIdx.x * GCH;
  const int cols = min(GCH, DTOT - c0);
  for (int idx = threadIdx.x; idx < 64 * GCH; idx += 256) {
    const int i = idx >> 7, dd = idx & 127;
    Vs[i * 129 + dd] = (dd < cols) ? vout[(size_t)i * DTOT + c0 + dd] : 0.f;
  }
  for (int q = threadIdx.x; q < 4096; q += 256) kds[q] = kd[q];
  if (threadIdx.x < 64) ss[threadIdx.x] = s[threadIdx.x];
  __syncthreads();
  const int col = threadIdx.x & 127;
  const int ihalf = threadIdx.x >> 7;
  if (col < cols) {
    const int d = c0 + col;
    float acc[32] = {};
    for (int j = 0; j < 64; ++j) {
      const float v = Vs[j * 129 + col];
      #pragma unroll
      for (int a = 0; a < 32; ++a)
        acc[a] = fmaf(kds[(ihalf * 32 + a) * 64 + j], v, acc[a]);
    }
    #pragma unroll
    for (int a = 0; a < 32; ++a) {
      const int i = ihalf * 32 + a;
      const float th = theta_at(i, d, W1, b1, W2, b2);
      vout[(size_t)i * DTOT + d] = th * (1.f + STEPC * ss[i]) + STEPC * acc[a];
    }
  }
}

extern "C" void kernel_launch(void* const* d_in, const int* in_sizes, int n_in,
                              void* d_out, int out_size, void* d_ws, size_t ws_size,
                              hipStream_t stream) {
  const float* W1 = (const float*)d_in[0];
  const float* b1 = (const float*)d_in[1];
  const float* W2 = (const float*)d_in[2];
  const float* b2 = (const float*)d_in[3];
  const float* X  = (const float*)d_in[4];
  const float* y  = (const float*)d_in[5];
  float* vout = (float*)d_out;

  float* e_ws  = (float*)d_ws;            // 64*2048
  float* Pb2   = e_ws + NP * BATCH;       // 512
  float* gpart = Pb2 + 512;               // 145*4096
  float* gram  = gpart + NGBLK * 4096;    // 4096
  float* kd    = gram + 4096;             // 4096
  float* s     = kd + 4096;               // 64

  k_fwd<<<dim3(NP, 8), 512, 0, stream>>>(W1, b1, W2, b2, X, y, e_ws, Pb2);
  k_bwd<<<dim3(NP, 8), 512, 0, stream>>>(W1, b1, W2, b2, X, e_ws, Pb2, vout);
  k_gram_partial<<<NGBLK, 256, 0, stream>>>(W1, b1, W2, b2, gpart);
  k_gram_reduce<<<16, 256, 0, stream>>>(gpart, gram);
  k_kd<<<1, 256, 0, stream>>>(gram, kd, s);
  k_update<<<NGBLK, 256, 0, stream>>>(W1, b1, W2, b2, kd, s, vout);
}

// Round 3
// 131.037 us; speedup vs baseline: 3.2691x; 1.3245x over previous
//
#include <hip/hip_runtime.h>

#define NP 64
#define HID 1024
#define DIN 16
#define BATCH 2048
#define DTOT 18433
#define OFF_B1 16384
#define OFF_W2 17408
#define OFF_B2 18432
#define STEPC 0.0015625f  /* 0.1/64 */
#define GCH 128
#define NGBLK 145  /* ceil(18433/128) */

typedef __attribute__((ext_vector_type(8))) short bf16x8;
typedef __attribute__((ext_vector_type(4))) short short4v;
typedef __attribute__((ext_vector_type(4))) float f32x4;

__device__ __forceinline__ short f2bf(float f) {
  union { float f; unsigned u; } v; v.f = f;
  unsigned r = v.u + 0x7FFFu + ((v.u >> 16) & 1u);
  return (short)(r >> 16);
}

__device__ __forceinline__ float theta_at(int i, int d,
    const float* __restrict__ W1, const float* __restrict__ b1,
    const float* __restrict__ W2, const float* __restrict__ b2) {
  if (d < OFF_B1) return W1[i * 16384 + d];
  if (d < OFF_W2) return b1[i * HID + (d - OFF_B1)];
  if (d < OFF_B2) return W2[i * HID + (d - OFF_W2)];
  return b2[i];
}

// K0: one-time bf16 conversions. grid(512) x 256.
// W1b: row-major bf16 of W1. Xb: row-major bf16 of X.
// XtS: swizzled X^T image, element (d*2048+b) ^ ((d&7)<<3).
__global__ __launch_bounds__(256) void k_prep(
    const float* __restrict__ W1, const float* __restrict__ X,
    short* __restrict__ W1b, short* __restrict__ Xb, short* __restrict__ XtS) {
  const int gid = blockIdx.x * 256 + threadIdx.x;  // 131072 threads
  {
    const size_t base = (size_t)gid * 8;
    f32x4 a = *(const f32x4*)&W1[base];
    f32x4 b = *(const f32x4*)&W1[base + 4];
    bf16x8 o;
    o[0] = f2bf(a[0]); o[1] = f2bf(a[1]); o[2] = f2bf(a[2]); o[3] = f2bf(a[3]);
    o[4] = f2bf(b[0]); o[5] = f2bf(b[1]); o[6] = f2bf(b[2]); o[7] = f2bf(b[3]);
    *(bf16x8*)&W1b[base] = o;
  }
  if (gid < 4096) {
    const size_t base = (size_t)gid * 8;
    f32x4 a = *(const f32x4*)&X[base];
    f32x4 b = *(const f32x4*)&X[base + 4];
    bf16x8 o;
    o[0] = f2bf(a[0]); o[1] = f2bf(a[1]); o[2] = f2bf(a[2]); o[3] = f2bf(a[3]);
    o[4] = f2bf(b[0]); o[5] = f2bf(b[1]); o[6] = f2bf(b[2]); o[7] = f2bf(b[3]);
    *(bf16x8*)&Xb[base] = o;
  }
  if (gid < 2048) {
    const int d = gid & 15;
    const int b0 = (gid >> 4) * 16;
    short tmp[16];
    #pragma unroll
    for (int i = 0; i < 16; ++i) tmp[i] = f2bf(X[(b0 + i) * DIN + d]);
    const int ebase = d * 2048 + b0;
    const int x = (d & 7) << 3;
    #pragma unroll
    for (int q = 0; q < 4; ++q) {
      short4v s4 = {tmp[q * 4], tmp[q * 4 + 1], tmp[q * 4 + 2], tmp[q * 4 + 3]};
      *(short4v*)&XtS[(ebase + q * 4) ^ x] = s4;
    }
  }
}

// K1: forward. grid(64 n, 8 bg) x 512. mfma(A=W1-rows, B=X-rows) -> C[k][b];
// k-sum in-register + 2 shfl; one LDS reduce per block.
__global__ __launch_bounds__(512) void k_fwd(
    const short* __restrict__ W1b, const float* __restrict__ b1,
    const float* __restrict__ W2, const float* __restrict__ b2,
    const short* __restrict__ Xb, const float* __restrict__ y,
    float* __restrict__ e_ws, float* __restrict__ Pb2) {
  const int n = blockIdx.x, bg = blockIdx.y;
  const int tid = threadIdx.x;
  const int w = tid >> 6, l = tid & 63;
  const int lrow = l & 15, lhi = l >> 4;
  __shared__ float yhp[8][256];
  __shared__ float pbl[4];

  const bf16x8 zf = {0, 0, 0, 0, 0, 0, 0, 0};
  bf16x8 af[8];
  f32x4 b1v[8], w2v[8];
  #pragma unroll
  for (int ktl = 0; ktl < 8; ++ktl) {
    const int krow = n * HID + (w * 8 + ktl) * 16;
    af[ktl] = (lhi < 2) ? *(const bf16x8*)&W1b[(size_t)(krow + lrow) * DIN + lhi * 8] : zf;
    b1v[ktl] = *(const f32x4*)&b1[krow + lhi * 4];
    w2v[ktl] = *(const f32x4*)&W2[krow + lhi * 4];
  }

  for (int bt = 0; bt < 16; ++bt) {
    const int bbase = bg * 256 + bt * 16;
    const bf16x8 bf = (lhi < 2) ? *(const bf16x8*)&Xb[(size_t)(bbase + lrow) * DIN + lhi * 8] : zf;
    float ya = 0.f;
    #pragma unroll
    for (int ktl = 0; ktl < 8; ++ktl) {
      f32x4 c = {0.f, 0.f, 0.f, 0.f};
      c = __builtin_amdgcn_mfma_f32_16x16x32_bf16(af[ktl], bf, c, 0, 0, 0);
      #pragma unroll
      for (int r = 0; r < 4; ++r) {
        const float pre = c[r] + b1v[ktl][r];
        ya = fmaf(fmaxf(pre, 0.f), w2v[ktl][r], ya);
      }
    }
    ya += __shfl_xor(ya, 16);
    ya += __shfl_xor(ya, 32);
    if (l < 16) yhp[w][bt * 16 + lrow] = ya;
  }
  __syncthreads();
  float ev = 0.f;
  if (tid < 256) {
    float sum = 0.f;
    #pragma unroll
    for (int q = 0; q < 8; ++q) sum += yhp[q][tid];
    const int b = bg * 256 + tid;
    ev = y[b] - (sum + b2[n]);
    e_ws[n * BATCH + b] = ev;
  }
  #pragma unroll
  for (int off = 1; off < 64; off <<= 1) ev += __shfl_xor(ev, off);
  if (tid < 256 && l == 0) pbl[w] = ev;
  __syncthreads();
  if (tid == 0) Pb2[n * 8 + bg] = pbl[0] + pbl[1] + pbl[2] + pbl[3];
}

// K2: backward. grid(64 n, 8 kg) x 512. Barrier-free inner loop: private
// per-wave Gt; Xt staged once from pre-swizzled global image.
__global__ __launch_bounds__(512) void k_bwd(
    const float* __restrict__ W1, const float* __restrict__ b1,
    const float* __restrict__ W2, const float* __restrict__ b2,
    const short* __restrict__ W1b, const short* __restrict__ Xb,
    const short* __restrict__ XtS, const float* __restrict__ e_ws,
    const float* __restrict__ Pb2, float* __restrict__ vout) {
  const int n = blockIdx.x, kg = blockIdx.y;
  const int tid = threadIdx.x;
  const int w = tid >> 6, l = tid & 63;
  const int lrow = l & 15, lhi = l >> 4;
  __shared__ short Xt[16 * 2048];  // 64KB, same swizzle as XtS
  __shared__ short Gt[8 * 512];    // 1KB per wave, private

  #pragma unroll
  for (int i = 0; i < 8; ++i) {
    const int idx = (i * 512 + tid) * 8;
    *(bf16x8*)&Xt[idx] = *(const bf16x8*)&XtS[idx];
  }

  const int kt_g = kg * 8 + w;
  const int kglob = kt_g * 16 + lrow;
  const bf16x8 zf = {0, 0, 0, 0, 0, 0, 0, 0};
  const bf16x8 b1f = (lhi < 2) ? *(const bf16x8*)&W1b[(size_t)(n * HID + kglob) * DIN + lhi * 8] : zf;
  const float b1r = b1[n * HID + kglob];
  const float w2r = W2[n * HID + kglob];
  short* __restrict__ GtW = &Gt[w * 512];
  const int xw = (lrow & 7) << 3;
  f32x4 c2 = {0.f, 0.f, 0.f, 0.f};
  float gw2a = 0.f, gb1a = 0.f;
  __syncthreads();

  for (int bt = 0; bt < 64; ++bt) {
    #pragma unroll
    for (int rt = 0; rt < 2; ++rt) {
      const int brow = bt * 32 + rt * 16 + lrow;
      const bf16x8 a1 = (lhi < 2) ? *(const bf16x8*)&Xb[(size_t)brow * DIN + lhi * 8] : zf;
      f32x4 c1 = {0.f, 0.f, 0.f, 0.f};
      c1 = __builtin_amdgcn_mfma_f32_16x16x32_bf16(a1, b1f, c1, 0, 0, 0);
      const f32x4 ef = *(const f32x4*)&e_ws[n * BATCH + bt * 32 + rt * 16 + lhi * 4];
      short4v g4;
      #pragma unroll
      for (int r = 0; r < 4; ++r) {
        const float pre = c1[r] + b1r;
        gw2a = fmaf(ef[r], fmaxf(pre, 0.f), gw2a);
        const float g = (pre > 0.f) ? ef[r] * w2r : 0.f;
        gb1a += g;
        g4[r] = f2bf(g);
      }
      *(short4v*)&GtW[(lrow * 32 + rt * 16 + lhi * 4) ^ xw] = g4;
    }
    asm volatile("s_waitcnt lgkmcnt(0)" ::: "memory");
    const bf16x8 a2f = *(const bf16x8*)&GtW[(lrow * 32 + lhi * 8) ^ xw];
    const bf16x8 b2f = *(const bf16x8*)&Xt[(lrow * 2048 + bt * 32 + lhi * 8) ^ xw];
    c2 = __builtin_amdgcn_mfma_f32_16x16x32_bf16(a2f, b2f, c2, 0, 0, 0);
  }

  gw2a += __shfl_xor(gw2a, 16); gw2a += __shfl_xor(gw2a, 32);
  gb1a += __shfl_xor(gb1a, 16); gb1a += __shfl_xor(gb1a, 32);

  #pragma unroll
  for (int r = 0; r < 4; ++r) {
    const int k = kt_g * 16 + lhi * 4 + r;
    vout[(size_t)n * DTOT + (size_t)k * 16 + lrow] =
        c2[r] - 2.f * W1[(n * HID + k) * DIN + lrow];
  }
  if (l < 16) {
    const int k = kt_g * 16 + l;
    vout[(size_t)n * DTOT + OFF_B1 + k] = gb1a - 2.f * b1[n * HID + k];
    vout[(size_t)n * DTOT + OFF_W2 + k] = gw2a - 2.f * W2[n * HID + k];
  }
  if (kg == 0 && tid == 0) {
    float sb = 0.f;
    #pragma unroll
    for (int q = 0; q < 8; ++q) sb += Pb2[n * 8 + q];
    vout[(size_t)n * DTOT + OFF_B2] = sb - 2.f * b2[n];
  }
}

// K3: Gram partials per 128-column chunk. grid(145) x 256
__global__ __launch_bounds__(256) void k_gram_partial(
    const float* __restrict__ W1, const float* __restrict__ b1,
    const float* __restrict__ W2, const float* __restrict__ b2,
    float* __restrict__ gpart) {
  __shared__ float ths[64 * 129];
  const int c0 = blockIdx.x * GCH;
  const int cols = min(GCH, DTOT - c0);
  for (int idx = threadIdx.x; idx < 64 * GCH; idx += 256) {
    const int i = idx >> 7, dd = idx & 127;
    ths[i * 129 + dd] = (dd < cols) ? theta_at(i, c0 + dd, W1, b1, W2, b2) : 0.f;
  }
  __syncthreads();
  const int i0 = (threadIdx.x >> 4) << 2;
  const int j0 = (threadIdx.x & 15) << 2;
  float acc[4][4] = {};
  for (int dc = 0; dc < cols; ++dc) {
    const float ai0 = ths[(i0 + 0) * 129 + dc], ai1 = ths[(i0 + 1) * 129 + dc];
    const float ai2 = ths[(i0 + 2) * 129 + dc], ai3 = ths[(i0 + 3) * 129 + dc];
    const float bj0 = ths[(j0 + 0) * 129 + dc], bj1 = ths[(j0 + 1) * 129 + dc];
    const float bj2 = ths[(j0 + 2) * 129 + dc], bj3 = ths[(j0 + 3) * 129 + dc];
    acc[0][0] = fmaf(ai0, bj0, acc[0][0]); acc[0][1] = fmaf(ai0, bj1, acc[0][1]);
    acc[0][2] = fmaf(ai0, bj2, acc[0][2]); acc[0][3] = fmaf(ai0, bj3, acc[0][3]);
    acc[1][0] = fmaf(ai1, bj0, acc[1][0]); acc[1][1] = fmaf(ai1, bj1, acc[1][1]);
    acc[1][2] = fmaf(ai1, bj2, acc[1][2]); acc[1][3] = fmaf(ai1, bj3, acc[1][3]);
    acc[2][0] = fmaf(ai2, bj0, acc[2][0]); acc[2][1] = fmaf(ai2, bj1, acc[2][1]);
    acc[2][2] = fmaf(ai2, bj2, acc[2][2]); acc[2][3] = fmaf(ai2, bj3, acc[2][3]);
    acc[3][0] = fmaf(ai3, bj0, acc[3][0]); acc[3][1] = fmaf(ai3, bj1, acc[3][1]);
    acc[3][2] = fmaf(ai3, bj2, acc[3][2]); acc[3][3] = fmaf(ai3, bj3, acc[3][3]);
  }
  float* __restrict__ gp = gpart + blockIdx.x * 4096;
  #pragma unroll
  for (int a = 0; a < 4; ++a)
    #pragma unroll
    for (int bj = 0; bj < 4; ++bj)
      gp[(i0 + a) * 64 + j0 + bj] = acc[a][bj];
}

// K4a: reduce Gram partials. grid(16) x 256
__global__ __launch_bounds__(256) void k_gram_reduce(
    const float* __restrict__ gpart, float* __restrict__ gram) {
  const int pair = blockIdx.x * 256 + threadIdx.x;
  float a = 0.f;
  for (int p = 0; p < NGBLK; ++p) a += gpart[p * 4096 + pair];
  gram[pair] = a;
}

// K4b: kd = exp(-d2/2), s = row sums. grid(1) x 256
__global__ __launch_bounds__(256) void k_kd(
    const float* __restrict__ gram, float* __restrict__ kd, float* __restrict__ s) {
  __shared__ float kds[4096];
  __shared__ float sq[64];
  if (threadIdx.x < 64) sq[threadIdx.x] = gram[threadIdx.x * 65];
  __syncthreads();
  for (int q = threadIdx.x; q < 4096; q += 256) {
    const int i = q >> 6, j = q & 63;
    const float d2 = fmaxf(sq[i] + sq[j] - 2.f * gram[q], 0.f);
    const float kv = expf(-0.5f * d2);
    kds[q] = kv;
    kd[q] = kv;
  }
  __syncthreads();
  if (threadIdx.x < 64) {
    float a = 0.f;
    for (int j = 0; j < 64; ++j) a += kds[threadIdx.x * 64 + j];
    s[threadIdx.x] = a;
  }
}

// K5: out[i,d] = theta[i,d]*(1+c*s[i]) + c*sum_j kd[i,j]*V[j,d].
// grid(145) x 256; thread = (colq 0..31)*(ig 0..7), acc[8 i] x f32x4 cols.
__global__ __launch_bounds__(256) void k_update(
    const float* __restrict__ W1, const float* __restrict__ b1,
    const float* __restrict__ W2, const float* __restrict__ b2,
    const float* __restrict__ kd, const float* __restrict__ s,
    float* __restrict__ vout) {
  __shared__ float Vs[64][132];
  __shared__ float kds[4096];
  __shared__ float ss[64];
  const int c0 = blockIdx.x * GCH;
  const int cols = min(GCH, DTOT - c0);
  for (int idx = threadIdx.x; idx < 64 * GCH; idx += 256) {
    const int i = idx >> 7, dd = idx & 127;
    Vs[i][dd] = (dd < cols) ? vout[(size_t)i * DTOT + c0 + dd] : 0.f;
  }
  for (int q = threadIdx.x; q < 4096; q += 256) kds[q] = kd[q];
  if (threadIdx.x < 64) ss[threadIdx.x] = s[threadIdx.x];
  __syncthreads();
  const int col4 = (threadIdx.x & 31) * 4;
  const int i0 = (threadIdx.x >> 5) * 8;
  f32x4 acc[8] = {};
  for (int j = 0; j < 64; ++j) {
    const f32x4 vv = *(const f32x4*)&Vs[j][col4];
    #pragma unroll
    for (int a = 0; a < 8; ++a) {
      const float kv = kds[(i0 + a) * 64 + j];
      acc[a][0] = fmaf(kv, vv[0], acc[a][0]);
      acc[a][1] = fmaf(kv, vv[1], acc[a][1]);
      acc[a][2] = fmaf(kv, vv[2], acc[a][2]);
      acc[a][3] = fmaf(kv, vv[3], acc[a][3]);
    }
  }
  #pragma unroll
  for (int a = 0; a < 8; ++a) {
    const int i = i0 + a;
    const float f = 1.f + STEPC * ss[i];
    #pragma unroll
    for (int cc = 0; cc < 4; ++cc) {
      const int d = c0 + col4 + cc;
      if (d < DTOT) {
        const float th = theta_at(i, d, W1, b1, W2, b2);
        vout[(size_t)i * DTOT + d] = th * f + STEPC * acc[a][cc];
      }
    }
  }
}

extern "C" void kernel_launch(void* const* d_in, const int* in_sizes, int n_in,
                              void* d_out, int out_size, void* d_ws, size_t ws_size,
                              hipStream_t stream) {
  const float* W1 = (const float*)d_in[0];
  const float* b1 = (const float*)d_in[1];
  const float* W2 = (const float*)d_in[2];
  const float* b2 = (const float*)d_in[3];
  const float* X  = (const float*)d_in[4];
  const float* y  = (const float*)d_in[5];
  float* vout = (float*)d_out;

  float* e_ws  = (float*)d_ws;            // 131072
  float* Pb2   = e_ws + NP * BATCH;       // 512
  float* gpart = Pb2 + 512;               // 145*4096
  float* gram  = gpart + NGBLK * 4096;    // 4096
  float* kd    = gram + 4096;             // 4096
  float* s     = kd + 4096;               // 64
  short* W1b   = (short*)(s + 64);        // 1048576
  short* Xb    = W1b + NP * HID * DIN;    // 32768
  short* XtS   = Xb + BATCH * DIN;        // 32768

  k_prep<<<512, 256, 0, stream>>>(W1, X, W1b, Xb, XtS);
  k_fwd<<<dim3(NP, 8), 512, 0, stream>>>(W1b, b1, W2, b2, Xb, y, e_ws, Pb2);
  k_bwd<<<dim3(NP, 8), 512, 0, stream>>>(W1, b1, W2, b2, W1b, Xb, XtS, e_ws, Pb2, vout);
  k_gram_partial<<<NGBLK, 256, 0, stream>>>(W1, b1, W2, b2, gpart);
  k_gram_reduce<<<16, 256, 0, stream>>>(gpart, gram);
  k_kd<<<1, 256, 0, stream>>>(gram, kd, s);
  k_update<<<NGBLK, 256, 0, stream>>>(W1, b1, W2, b2, kd, s, vout);
}

// Round 4
// 124.985 us; speedup vs baseline: 3.4274x; 1.0484x over previous
//
#include <hip/hip_runtime.h>

#define NP 64
#define HID 1024
#define DIN 16
#define BATCH 2048
#define DTOT 18433
#define OFF_B1 16384
#define OFF_W2 17408
#define OFF_B2 18432
#define STEPC 0.0015625f  /* 0.1/64 */
#define GCH 128
#define NGBLK 145  /* ceil(18433/128) */

typedef __attribute__((ext_vector_type(8))) short bf16x8;
typedef __attribute__((ext_vector_type(4))) short short4v;
typedef __attribute__((ext_vector_type(4))) float f32x4;

__device__ __forceinline__ short f2bf(float f) {
  union { float f; unsigned u; } v; v.f = f;
  unsigned r = v.u + 0x7FFFu + ((v.u >> 16) & 1u);
  return (short)(r >> 16);
}

__device__ __forceinline__ float theta_at(int i, int d,
    const float* __restrict__ W1, const float* __restrict__ b1,
    const float* __restrict__ W2, const float* __restrict__ b2) {
  if (d < OFF_B1) return W1[i * 16384 + d];
  if (d < OFF_W2) return b1[i * HID + (d - OFF_B1)];
  if (d < OFF_B2) return W2[i * HID + (d - OFF_W2)];
  return b2[i];
}

// K0: one-time bf16 conversions. grid(512) x 256.
__global__ __launch_bounds__(256) void k_prep(
    const float* __restrict__ W1, const float* __restrict__ X,
    short* __restrict__ W1b, short* __restrict__ Xb, short* __restrict__ XtS) {
  const int gid = blockIdx.x * 256 + threadIdx.x;  // 131072 threads
  {
    const size_t base = (size_t)gid * 8;
    f32x4 a = *(const f32x4*)&W1[base];
    f32x4 b = *(const f32x4*)&W1[base + 4];
    bf16x8 o;
    o[0] = f2bf(a[0]); o[1] = f2bf(a[1]); o[2] = f2bf(a[2]); o[3] = f2bf(a[3]);
    o[4] = f2bf(b[0]); o[5] = f2bf(b[1]); o[6] = f2bf(b[2]); o[7] = f2bf(b[3]);
    *(bf16x8*)&W1b[base] = o;
  }
  if (gid < 4096) {
    const size_t base = (size_t)gid * 8;
    f32x4 a = *(const f32x4*)&X[base];
    f32x4 b = *(const f32x4*)&X[base + 4];
    bf16x8 o;
    o[0] = f2bf(a[0]); o[1] = f2bf(a[1]); o[2] = f2bf(a[2]); o[3] = f2bf(a[3]);
    o[4] = f2bf(b[0]); o[5] = f2bf(b[1]); o[6] = f2bf(b[2]); o[7] = f2bf(b[3]);
    *(bf16x8*)&Xb[base] = o;
  }
  if (gid < 2048) {
    const int d = gid & 15;
    const int b0 = (gid >> 4) * 16;
    short tmp[16];
    #pragma unroll
    for (int i = 0; i < 16; ++i) tmp[i] = f2bf(X[(b0 + i) * DIN + d]);
    const int ebase = d * 2048 + b0;
    const int x = (d & 7) << 3;
    #pragma unroll
    for (int q = 0; q < 4; ++q) {
      short4v s4 = {tmp[q * 4], tmp[q * 4 + 1], tmp[q * 4 + 2], tmp[q * 4 + 3]};
      *(short4v*)&XtS[(ebase + q * 4) ^ x] = s4;
    }
  }
}

// K1: forward. grid(64 n, 8 bg) x 512. Writes e (fp32) and ebf (bf16).
__global__ __launch_bounds__(512) void k_fwd(
    const short* __restrict__ W1b, const float* __restrict__ b1,
    const float* __restrict__ W2, const float* __restrict__ b2,
    const short* __restrict__ Xb, const float* __restrict__ y,
    float* __restrict__ e_ws, short* __restrict__ ebf_ws,
    float* __restrict__ Pb2) {
  const int n = blockIdx.x, bg = blockIdx.y;
  const int tid = threadIdx.x;
  const int w = tid >> 6, l = tid & 63;
  const int lrow = l & 15, lhi = l >> 4;
  __shared__ float yhp[8][256];
  __shared__ float pbl[4];

  const bf16x8 zf = {0, 0, 0, 0, 0, 0, 0, 0};
  bf16x8 af[8];
  f32x4 b1v[8], w2v[8];
  #pragma unroll
  for (int ktl = 0; ktl < 8; ++ktl) {
    const int krow = n * HID + (w * 8 + ktl) * 16;
    af[ktl] = (lhi < 2) ? *(const bf16x8*)&W1b[(size_t)(krow + lrow) * DIN + lhi * 8] : zf;
    b1v[ktl] = *(const f32x4*)&b1[krow + lhi * 4];
    w2v[ktl] = *(const f32x4*)&W2[krow + lhi * 4];
  }

  for (int bt = 0; bt < 16; ++bt) {
    const int bbase = bg * 256 + bt * 16;
    const bf16x8 bf = (lhi < 2) ? *(const bf16x8*)&Xb[(size_t)(bbase + lrow) * DIN + lhi * 8] : zf;
    float ya = 0.f;
    #pragma unroll
    for (int ktl = 0; ktl < 8; ++ktl) {
      f32x4 c = {0.f, 0.f, 0.f, 0.f};
      c = __builtin_amdgcn_mfma_f32_16x16x32_bf16(af[ktl], bf, c, 0, 0, 0);
      #pragma unroll
      for (int r = 0; r < 4; ++r) {
        const float pre = c[r] + b1v[ktl][r];
        ya = fmaf(fmaxf(pre, 0.f), w2v[ktl][r], ya);
      }
    }
    ya += __shfl_xor(ya, 16);
    ya += __shfl_xor(ya, 32);
    if (l < 16) yhp[w][bt * 16 + lrow] = ya;
  }
  __syncthreads();
  float ev = 0.f;
  if (tid < 256) {
    float sum = 0.f;
    #pragma unroll
    for (int q = 0; q < 8; ++q) sum += yhp[q][tid];
    const int b = bg * 256 + tid;
    ev = y[b] - (sum + b2[n]);
    e_ws[n * BATCH + b] = ev;
    ebf_ws[n * BATCH + b] = f2bf(ev);
  }
  #pragma unroll
  for (int off = 1; off < 64; off <<= 1) ev += __shfl_xor(ev, off);
  if (tid < 256 && l == 0) pbl[w] = ev;
  __syncthreads();
  if (tid == 0) Pb2[n * 8 + bg] = pbl[0] + pbl[1] + pbl[2] + pbl[3];
}

// K2: backward. grid(64 n, 8 kg) x 512. Factored G (w2 scaling in epilogue),
// software-pipelined WAR loop (same-wave DS in-order; no explicit drain).
__global__ __launch_bounds__(512) void k_bwd(
    const float* __restrict__ W1, const float* __restrict__ b1,
    const float* __restrict__ W2, const float* __restrict__ b2,
    const short* __restrict__ W1b, const short* __restrict__ Xb,
    const short* __restrict__ XtS, const float* __restrict__ e_ws,
    const short* __restrict__ ebf_ws, const float* __restrict__ Pb2,
    float* __restrict__ vout) {
  const int n = blockIdx.x, kg = blockIdx.y;
  const int tid = threadIdx.x;
  const int w = tid >> 6, l = tid & 63;
  const int lrow = l & 15, lhi = l >> 4;
  __shared__ short Xt[16 * 2048];  // 64KB, swizzled as XtS
  __shared__ short Gt[8 * 512];    // 1KB per wave, private

  #pragma unroll
  for (int i = 0; i < 8; ++i) {
    const int idx = (i * 512 + tid) * 8;
    *(bf16x8*)&Xt[idx] = *(const bf16x8*)&XtS[idx];
  }

  const int kt_g = kg * 8 + w;
  const int kglob = kt_g * 16 + lrow;
  const bf16x8 zf = {0, 0, 0, 0, 0, 0, 0, 0};
  const bf16x8 b1f = (lhi < 2) ? *(const bf16x8*)&W1b[(size_t)(n * HID + kglob) * DIN + lhi * 8] : zf;
  const float b1r = b1[n * HID + kglob];
  const float w2r = W2[n * HID + kglob];
  short* __restrict__ GtW = &Gt[w * 512];
  const int xw = (lrow & 7) << 3;
  f32x4 c2 = {0.f, 0.f, 0.f, 0.f};
  float gw2a = 0.f, gb1a = 0.f;
  short4v g4[2];

  auto computeG = [&](int btn) {
    #pragma unroll
    for (int rt = 0; rt < 2; ++rt) {
      const int brow = btn * 32 + rt * 16 + lrow;
      const bf16x8 a1 = (lhi < 2) ? *(const bf16x8*)&Xb[(size_t)brow * DIN + lhi * 8] : zf;
      f32x4 c1 = {0.f, 0.f, 0.f, 0.f};
      c1 = __builtin_amdgcn_mfma_f32_16x16x32_bf16(a1, b1f, c1, 0, 0, 0);
      const int eb = n * BATCH + btn * 32 + rt * 16 + lhi * 4;
      const f32x4 ef = *(const f32x4*)&e_ws[eb];
      const short4v es = *(const short4v*)&ebf_ws[eb];
      short4v gg;
      #pragma unroll
      for (int r = 0; r < 4; ++r) {
        const float pre = c1[r] + b1r;
        const bool m = pre > 0.f;
        const float me = m ? ef[r] : 0.f;
        gb1a += me;
        gw2a = fmaf(me, pre, gw2a);
        gg[r] = m ? es[r] : (short)0;
      }
      g4[rt] = gg;
    }
  };

  __syncthreads();
  computeG(0);

  for (int bt = 0; bt < 63; ++bt) {
    // write G(bt) (computed last iteration / prologue)
    *(short4v*)&GtW[(lrow * 32 + lhi * 4) ^ xw] = g4[0];
    *(short4v*)&GtW[(lrow * 32 + 16 + lhi * 4) ^ xw] = g4[1];
    // read fragments (in-order DS => sees the writes above)
    const bf16x8 a2f = *(const bf16x8*)&GtW[(lrow * 32 + lhi * 8) ^ xw];
    const bf16x8 b2f = *(const bf16x8*)&Xt[(lrow * 2048 + bt * 32 + lhi * 8) ^ xw];
    // overlap: compute next G while reads are in flight
    computeG(bt + 1);
    c2 = __builtin_amdgcn_mfma_f32_16x16x32_bf16(a2f, b2f, c2, 0, 0, 0);
  }
  {
    *(short4v*)&GtW[(lrow * 32 + lhi * 4) ^ xw] = g4[0];
    *(short4v*)&GtW[(lrow * 32 + 16 + lhi * 4) ^ xw] = g4[1];
    const bf16x8 a2f = *(const bf16x8*)&GtW[(lrow * 32 + lhi * 8) ^ xw];
    const bf16x8 b2f = *(const bf16x8*)&Xt[(lrow * 2048 + 63 * 32 + lhi * 8) ^ xw];
    c2 = __builtin_amdgcn_mfma_f32_16x16x32_bf16(a2f, b2f, c2, 0, 0, 0);
  }

  gw2a += __shfl_xor(gw2a, 16); gw2a += __shfl_xor(gw2a, 32);
  gb1a += __shfl_xor(gb1a, 16); gb1a += __shfl_xor(gb1a, 32);

  // dW1 rows: C2 row = lhi*4+r (k within tile), col = lrow (d); scale by w2[k]
  const f32x4 w2q = *(const f32x4*)&W2[n * HID + kt_g * 16 + lhi * 4];
  #pragma unroll
  for (int r = 0; r < 4; ++r) {
    const int k = kt_g * 16 + lhi * 4 + r;
    vout[(size_t)n * DTOT + (size_t)k * 16 + lrow] =
        c2[r] * w2q[r] - 2.f * W1[(n * HID + k) * DIN + lrow];
  }
  if (l < 16) {
    const int k = kt_g * 16 + l;
    vout[(size_t)n * DTOT + OFF_B1 + k] = gb1a * w2r - 2.f * b1[n * HID + k];
    vout[(size_t)n * DTOT + OFF_W2 + k] = gw2a - 2.f * W2[n * HID + k];
  }
  if (kg == 0 && tid == 0) {
    float sb = 0.f;
    #pragma unroll
    for (int q = 0; q < 8; ++q) sb += Pb2[n * 8 + q];
    vout[(size_t)n * DTOT + OFF_B2] = sb - 2.f * b2[n];
  }
}

// K3: Gram partials per 128-column chunk. grid(145) x 256.
// Transposed LDS [dc][i] + f32x4 reads.
__global__ __launch_bounds__(256) void k_gram_partial(
    const float* __restrict__ W1, const float* __restrict__ b1,
    const float* __restrict__ W2, const float* __restrict__ b2,
    float* __restrict__ gpart) {
  __shared__ float ths[128][68];
  const int c0 = blockIdx.x * GCH;
  for (int idx = threadIdx.x; idx < 2048; idx += 256) {
    const int i = idx >> 5;            // 0..63
    const int dd = (idx & 31) * 4;     // 0..124
    const int d = c0 + dd;
    float v0, v1, v2, v3;
    if (d + 3 < DTOT) {
      f32x4 q;
      if (d < OFF_B1)      q = *(const f32x4*)&W1[i * 16384 + d];
      else if (d < OFF_W2) q = *(const f32x4*)&b1[i * HID + (d - OFF_B1)];
      else                 q = *(const f32x4*)&W2[i * HID + (d - OFF_W2)];
      v0 = q[0]; v1 = q[1]; v2 = q[2]; v3 = q[3];
    } else {
      v0 = (d     < DTOT) ? theta_at(i, d,     W1, b1, W2, b2) : 0.f;
      v1 = (d + 1 < DTOT) ? theta_at(i, d + 1, W1, b1, W2, b2) : 0.f;
      v2 = (d + 2 < DTOT) ? theta_at(i, d + 2, W1, b1, W2, b2) : 0.f;
      v3 = (d + 3 < DTOT) ? theta_at(i, d + 3, W1, b1, W2, b2) : 0.f;
    }
    ths[dd][i] = v0; ths[dd + 1][i] = v1; ths[dd + 2][i] = v2; ths[dd + 3][i] = v3;
  }
  __syncthreads();
  const int i0 = (threadIdx.x >> 4) << 2;
  const int j0 = (threadIdx.x & 15) << 2;
  float acc[4][4] = {};
  for (int dc = 0; dc < 128; ++dc) {
    const f32x4 av = *(const f32x4*)&ths[dc][i0];
    const f32x4 bv = *(const f32x4*)&ths[dc][j0];
    #pragma unroll
    for (int a = 0; a < 4; ++a)
      #pragma unroll
      for (int bj = 0; bj < 4; ++bj)
        acc[a][bj] = fmaf(av[a], bv[bj], acc[a][bj]);
  }
  float* __restrict__ gp = gpart + blockIdx.x * 4096;
  #pragma unroll
  for (int a = 0; a < 4; ++a)
    #pragma unroll
    for (int bj = 0; bj < 4; ++bj)
      gp[(i0 + a) * 64 + j0 + bj] = acc[a][bj];
}

// K4a: reduce Gram partials. grid(64) x 256, 4 p-slices per pair.
__global__ __launch_bounds__(256) void k_gram_reduce(
    const float* __restrict__ gpart, float* __restrict__ gram) {
  const int pl = threadIdx.x & 63;
  const int sl = threadIdx.x >> 6;
  const int pair = blockIdx.x * 64 + pl;
  float a = 0.f;
  for (int p = sl; p < NGBLK; p += 4) a += gpart[p * 4096 + pair];
  __shared__ float red[4][64];
  red[sl][pl] = a;
  __syncthreads();
  if (threadIdx.x < 64)
    gram[blockIdx.x * 64 + threadIdx.x] =
        red[0][threadIdx.x] + red[1][threadIdx.x] + red[2][threadIdx.x] + red[3][threadIdx.x];
}

// K4b: kd = exp(-d2/2), s = row sums. grid(1) x 256
__global__ __launch_bounds__(256) void k_kd(
    const float* __restrict__ gram, float* __restrict__ kd, float* __restrict__ s) {
  __shared__ float kds[4096];
  __shared__ float sq[64];
  if (threadIdx.x < 64) sq[threadIdx.x] = gram[threadIdx.x * 65];
  __syncthreads();
  for (int q = threadIdx.x; q < 4096; q += 256) {
    const int i = q >> 6, j = q & 63;
    const float d2 = fmaxf(sq[i] + sq[j] - 2.f * gram[q], 0.f);
    const float kv = expf(-0.5f * d2);
    kds[q] = kv;
    kd[q] = kv;
  }
  __syncthreads();
  if (threadIdx.x < 64) {
    float a = 0.f;
    for (int j = 0; j < 64; ++j) a += kds[threadIdx.x * 64 + j];
    s[threadIdx.x] = a;
  }
}

// K5: out[i,d] = theta[i,d]*(1+c*s[i]) + c*sum_j kd[i,j]*V[j,d].
// kd symmetric -> f32x4 kd reads. grid(145) x 256.
__global__ __launch_bounds__(256) void k_update(
    const float* __restrict__ W1, const float* __restrict__ b1,
    const float* __restrict__ W2, const float* __restrict__ b2,
    const float* __restrict__ kd, const float* __restrict__ s,
    float* __restrict__ vout) {
  __shared__ float Vs[64][132];
  __shared__ float kds[4096];
  __shared__ float ss[64];
  const int c0 = blockIdx.x * GCH;
  const int cols = min(GCH, DTOT - c0);
  for (int idx = threadIdx.x; idx < 64 * GCH; idx += 256) {
    const int i = idx >> 7, dd = idx & 127;
    Vs[i][dd] = (dd < cols) ? vout[(size_t)i * DTOT + c0 + dd] : 0.f;
  }
  for (int q = threadIdx.x; q < 4096; q += 256) kds[q] = kd[q];
  if (threadIdx.x < 64) ss[threadIdx.x] = s[threadIdx.x];
  __syncthreads();
  const int col4 = (threadIdx.x & 31) * 4;
  const int i0 = (threadIdx.x >> 5) * 8;
  f32x4 acc[8] = {};
  for (int j = 0; j < 64; ++j) {
    const f32x4 vv = *(const f32x4*)&Vs[j][col4];
    // kd[i][j] == kd[j][i]: read row j contiguously
    const f32x4 k0 = *(const f32x4*)&kds[j * 64 + i0];
    const f32x4 k1 = *(const f32x4*)&kds[j * 64 + i0 + 4];
    #pragma unroll
    for (int a = 0; a < 4; ++a) {
      acc[a][0] = fmaf(k0[a], vv[0], acc[a][0]);
      acc[a][1] = fmaf(k0[a], vv[1], acc[a][1]);
      acc[a][2] = fmaf(k0[a], vv[2], acc[a][2]);
      acc[a][3] = fmaf(k0[a], vv[3], acc[a][3]);
    }
    #pragma unroll
    for (int a = 0; a < 4; ++a) {
      acc[a + 4][0] = fmaf(k1[a], vv[0], acc[a + 4][0]);
      acc[a + 4][1] = fmaf(k1[a], vv[1], acc[a + 4][1]);
      acc[a + 4][2] = fmaf(k1[a], vv[2], acc[a + 4][2]);
      acc[a + 4][3] = fmaf(k1[a], vv[3], acc[a + 4][3]);
    }
  }
  #pragma unroll
  for (int a = 0; a < 8; ++a) {
    const int i = i0 + a;
    const float f = 1.f + STEPC * ss[i];
    #pragma unroll
    for (int cc = 0; cc < 4; ++cc) {
      const int d = c0 + col4 + cc;
      if (d < DTOT) {
        const float th = theta_at(i, d, W1, b1, W2, b2);
        vout[(size_t)i * DTOT + d] = th * f + STEPC * acc[a][cc];
      }
    }
  }
}

extern "C" void kernel_launch(void* const* d_in, const int* in_sizes, int n_in,
                              void* d_out, int out_size, void* d_ws, size_t ws_size,
                              hipStream_t stream) {
  const float* W1 = (const float*)d_in[0];
  const float* b1 = (const float*)d_in[1];
  const float* W2 = (const float*)d_in[2];
  const float* b2 = (const float*)d_in[3];
  const float* X  = (const float*)d_in[4];
  const float* y  = (const float*)d_in[5];
  float* vout = (float*)d_out;

  float* e_ws  = (float*)d_ws;            // 131072 f
  float* Pb2   = e_ws + NP * BATCH;       // 512 f
  float* gpart = Pb2 + 512;               // 145*4096 f
  float* gram  = gpart + NGBLK * 4096;    // 4096 f
  float* kd    = gram + 4096;             // 4096 f
  float* s     = kd + 4096;               // 64 f
  short* W1b   = (short*)(s + 64);        // 1048576 s
  short* Xb    = W1b + NP * HID * DIN;    // 32768 s
  short* XtS   = Xb + BATCH * DIN;        // 32768 s
  short* ebf   = XtS + BATCH * DIN;       // 131072 s

  k_prep<<<512, 256, 0, stream>>>(W1, X, W1b, Xb, XtS);
  k_fwd<<<dim3(NP, 8), 512, 0, stream>>>(W1b, b1, W2, b2, Xb, y, e_ws, ebf, Pb2);
  k_bwd<<<dim3(NP, 8), 512, 0, stream>>>(W1, b1, W2, b2, W1b, Xb, XtS, e_ws, ebf, Pb2, vout);
  k_gram_partial<<<NGBLK, 256, 0, stream>>>(W1, b1, W2, b2, gpart);
  k_gram_reduce<<<64, 256, 0, stream>>>(gpart, gram);
  k_kd<<<1, 256, 0, stream>>>(gram, kd, s);
  k_update<<<NGBLK, 256, 0, stream>>>(W1, b1, W2, b2, kd, s, vout);
}

// Round 5
// 117.215 us; speedup vs baseline: 3.6546x; 1.0663x over previous
//
#include <hip/hip_runtime.h>

#define NP 64
#define HID 1024
#define DIN 16
#define BATCH 2048
#define DTOT 18433
#define OFF_B1 16384
#define OFF_W2 17408
#define OFF_B2 18432
#define STEPC 0.0015625f  /* 0.1/64 */
#define GCH 128
#define NGBLK 145  /* ceil(18433/128) */

typedef __attribute__((ext_vector_type(8))) short bf16x8;
typedef __attribute__((ext_vector_type(4))) short short4v;
typedef __attribute__((ext_vector_type(4))) float f32x4;

__device__ __forceinline__ short f2bf(float f) {
  union { float f; unsigned u; } v; v.f = f;
  unsigned r = v.u + 0x7FFFu + ((v.u >> 16) & 1u);
  return (short)(r >> 16);
}

__device__ __forceinline__ float theta_at(int i, int d,
    const float* __restrict__ W1, const float* __restrict__ b1,
    const float* __restrict__ W2, const float* __restrict__ b2) {
  if (d < OFF_B1) return W1[i * 16384 + d];
  if (d < OFF_W2) return b1[i * HID + (d - OFF_B1)];
  if (d < OFF_B2) return W2[i * HID + (d - OFF_W2)];
  return b2[i];
}

// K0: one-time bf16 conversions. grid(512) x 256.
// W1b: row-major bf16 W1. Xb: row-major bf16 X. XtS: PLAIN X^T bf16 [16][2048].
__global__ __launch_bounds__(256) void k_prep(
    const float* __restrict__ W1, const float* __restrict__ X,
    short* __restrict__ W1b, short* __restrict__ Xb, short* __restrict__ XtS) {
  const int gid = blockIdx.x * 256 + threadIdx.x;  // 131072 threads
  {
    const size_t base = (size_t)gid * 8;
    f32x4 a = *(const f32x4*)&W1[base];
    f32x4 b = *(const f32x4*)&W1[base + 4];
    bf16x8 o;
    o[0] = f2bf(a[0]); o[1] = f2bf(a[1]); o[2] = f2bf(a[2]); o[3] = f2bf(a[3]);
    o[4] = f2bf(b[0]); o[5] = f2bf(b[1]); o[6] = f2bf(b[2]); o[7] = f2bf(b[3]);
    *(bf16x8*)&W1b[base] = o;
  }
  if (gid < 4096) {
    const size_t base = (size_t)gid * 8;
    f32x4 a = *(const f32x4*)&X[base];
    f32x4 b = *(const f32x4*)&X[base + 4];
    bf16x8 o;
    o[0] = f2bf(a[0]); o[1] = f2bf(a[1]); o[2] = f2bf(a[2]); o[3] = f2bf(a[3]);
    o[4] = f2bf(b[0]); o[5] = f2bf(b[1]); o[6] = f2bf(b[2]); o[7] = f2bf(b[3]);
    *(bf16x8*)&Xb[base] = o;
  }
  if (gid < 2048) {
    const int d = gid & 15;
    const int b0 = (gid >> 4) * 16;
    #pragma unroll
    for (int q = 0; q < 4; ++q) {
      short4v s4;
      #pragma unroll
      for (int t = 0; t < 4; ++t) s4[t] = f2bf(X[(b0 + q * 4 + t) * DIN + d]);
      *(short4v*)&XtS[d * 2048 + b0 + q * 4] = s4;
    }
  }
}

// K1: forward. grid(64 n, 8 bg) x 512. Writes ebf (bf16) and Pb2 partials.
__global__ __launch_bounds__(512) void k_fwd(
    const short* __restrict__ W1b, const float* __restrict__ b1,
    const float* __restrict__ W2, const float* __restrict__ b2,
    const short* __restrict__ Xb, const float* __restrict__ y,
    short* __restrict__ ebf_ws, float* __restrict__ Pb2) {
  const int n = blockIdx.x, bg = blockIdx.y;
  const int tid = threadIdx.x;
  const int w = tid >> 6, l = tid & 63;
  const int lrow = l & 15, lhi = l >> 4;
  __shared__ float yhp[8][256];
  __shared__ float pbl[4];

  const bf16x8 zf = {0, 0, 0, 0, 0, 0, 0, 0};
  bf16x8 af[8];
  f32x4 b1v[8], w2v[8];
  #pragma unroll
  for (int ktl = 0; ktl < 8; ++ktl) {
    const int krow = n * HID + (w * 8 + ktl) * 16;
    af[ktl] = (lhi < 2) ? *(const bf16x8*)&W1b[(size_t)(krow + lrow) * DIN + lhi * 8] : zf;
    b1v[ktl] = *(const f32x4*)&b1[krow + lhi * 4];
    w2v[ktl] = *(const f32x4*)&W2[krow + lhi * 4];
  }

  for (int bt = 0; bt < 16; ++bt) {
    const int bbase = bg * 256 + bt * 16;
    const bf16x8 bf = (lhi < 2) ? *(const bf16x8*)&Xb[(size_t)(bbase + lrow) * DIN + lhi * 8] : zf;
    float ya = 0.f;
    #pragma unroll
    for (int ktl = 0; ktl < 8; ++ktl) {
      f32x4 c = {0.f, 0.f, 0.f, 0.f};
      c = __builtin_amdgcn_mfma_f32_16x16x32_bf16(af[ktl], bf, c, 0, 0, 0);
      #pragma unroll
      for (int r = 0; r < 4; ++r) {
        const float pre = c[r] + b1v[ktl][r];
        ya = fmaf(fmaxf(pre, 0.f), w2v[ktl][r], ya);
      }
    }
    ya += __shfl_xor(ya, 16);
    ya += __shfl_xor(ya, 32);
    if (l < 16) yhp[w][bt * 16 + lrow] = ya;
  }
  __syncthreads();
  float ev = 0.f;
  if (tid < 256) {
    float sum = 0.f;
    #pragma unroll
    for (int q = 0; q < 8; ++q) sum += yhp[q][tid];
    const int b = bg * 256 + tid;
    ev = y[b] - (sum + b2[n]);
    ebf_ws[n * BATCH + b] = f2bf(ev);
  }
  #pragma unroll
  for (int off = 1; off < 64; off <<= 1) ev += __shfl_xor(ev, off);
  if (tid < 256 && l == 0) pbl[w] = ev;
  __syncthreads();
  if (tid == 0) Pb2[n * 8 + bg] = pbl[0] + pbl[1] + pbl[2] + pbl[3];
}

// K2: backward. grid(64 n, 8 kg) x 512.
// Inner loop: mask-only G (cmp+cndmask), gb1 via ones-MFMA; gw2 via epilogue
// identity gw2[k] = dot(dW1raw[k,:], W1[k,:]) + b1[k]*gb1[k].
__global__ __launch_bounds__(512) void k_bwd(
    const float* __restrict__ W1, const float* __restrict__ b1,
    const float* __restrict__ W2, const float* __restrict__ b2,
    const short* __restrict__ W1b, const short* __restrict__ Xb,
    const short* __restrict__ XtS, const short* __restrict__ ebf_ws,
    const float* __restrict__ Pb2, float* __restrict__ vout) {
  const int n = blockIdx.x, kg = blockIdx.y;
  const int tid = threadIdx.x;
  const int w = tid >> 6, l = tid & 63;
  const int lrow = l & 15, lhi = l >> 4;
  __shared__ short Gt[8 * 512];   // per-wave private G^T tile (swizzled)
  __shared__ short els[2048];     // this particle's ebf row

  // stage ebf row (4 shorts/thread)
  *(short4v*)&els[tid * 4] = *(const short4v*)&ebf_ws[n * BATCH + tid * 4];

  const int kt_g = kg * 8 + w;
  const int kglob = kt_g * 16 + lrow;
  const bf16x8 zf = {0, 0, 0, 0, 0, 0, 0, 0};
  const short one_bf = (short)0x3F80;
  const bf16x8 onesf = {one_bf, one_bf, one_bf, one_bf, one_bf, one_bf, one_bf, one_bf};
  const bf16x8 b1f = (lhi < 2) ? *(const bf16x8*)&W1b[(size_t)(n * HID + kglob) * DIN + lhi * 8] : zf;
  const float b1r = b1[n * HID + kglob];
  const float w2r = W2[n * HID + kglob];
  short* __restrict__ GtW = &Gt[w * 512];
  const int xw = (lrow & 7) << 3;
  f32x4 c2 = {0.f, 0.f, 0.f, 0.f};
  f32x4 c3 = {0.f, 0.f, 0.f, 0.f};

  // prefetch bt=0
  bf16x8 a1n0 = (lhi < 2) ? *(const bf16x8*)&Xb[(size_t)lrow * DIN + lhi * 8] : zf;
  bf16x8 a1n1 = (lhi < 2) ? *(const bf16x8*)&Xb[(size_t)(16 + lrow) * DIN + lhi * 8] : zf;
  bf16x8 b2fn = *(const bf16x8*)&XtS[lrow * 2048 + lhi * 8];
  __syncthreads();

  for (int bt = 0; bt < 64; ++bt) {
    const bf16x8 a10 = a1n0, a11 = a1n1, b2f = b2fn;
    // prefetch bt+1 (harmless over-read into adjacent ws buffers at bt=63)
    {
      const int bnext = (bt + 1) * 32;
      a1n0 = (lhi < 2) ? *(const bf16x8*)&Xb[(size_t)(bnext + lrow) * DIN + lhi * 8] : zf;
      a1n1 = (lhi < 2) ? *(const bf16x8*)&Xb[(size_t)(bnext + 16 + lrow) * DIN + lhi * 8] : zf;
      b2fn = *(const bf16x8*)&XtS[lrow * 2048 + bnext + lhi * 8];
    }
    // G for rt=0,1: g = pre>0 ? ebf : 0
    #pragma unroll
    for (int rt = 0; rt < 2; ++rt) {
      f32x4 c1 = {0.f, 0.f, 0.f, 0.f};
      c1 = __builtin_amdgcn_mfma_f32_16x16x32_bf16(rt ? a11 : a10, b1f, c1, 0, 0, 0);
      const short4v es = *(const short4v*)&els[bt * 32 + rt * 16 + lhi * 4];
      short4v gg;
      #pragma unroll
      for (int r = 0; r < 4; ++r) {
        const float pre = c1[r] + b1r;
        gg[r] = (pre > 0.f) ? es[r] : (short)0;
      }
      *(short4v*)&GtW[(lrow * 32 + rt * 16 + lhi * 4) ^ xw] = gg;
    }
    const bf16x8 a2f = *(const bf16x8*)&GtW[(lrow * 32 + lhi * 8) ^ xw];
    c2 = __builtin_amdgcn_mfma_f32_16x16x32_bf16(a2f, b2f, c2, 0, 0, 0);
    c3 = __builtin_amdgcn_mfma_f32_16x16x32_bf16(a2f, onesf, c3, 0, 0, 0);
  }

  // epilogue: dW1 write + gw2 dot partials
  const f32x4 w2q = *(const f32x4*)&W2[n * HID + kt_g * 16 + lhi * 4];
  float pr[4];
  #pragma unroll
  for (int r = 0; r < 4; ++r) {
    const int k = kt_g * 16 + lhi * 4 + r;
    const float w1val = W1[(n * HID + k) * DIN + lrow];
    vout[(size_t)n * DTOT + (size_t)k * 16 + lrow] = c2[r] * w2q[r] - 2.f * w1val;
    pr[r] = c2[r] * w1val;
  }
  // reduce dot over the 16 lrow lanes
  #pragma unroll
  for (int off = 1; off < 16; off <<= 1) {
    #pragma unroll
    for (int r = 0; r < 4; ++r) pr[r] += __shfl_xor(pr[r], off);
  }
  // redistribute: reader lane l<16 needs (r=l&3, lhi=l>>2); contribute own (lane&3)
  const int l3 = l & 3;
  const float pv = (l3 == 0) ? pr[0] : (l3 == 1) ? pr[1] : (l3 == 2) ? pr[2] : pr[3];
  const float gv = (l3 == 0) ? c3[0] : (l3 == 1) ? c3[1] : (l3 == 2) ? c3[2] : c3[3];
  const int src = (((l & 15) >> 2) << 4) | (l & 15);
  const float gw2dot = __shfl(pv, src);
  const float gb1v = __shfl(gv, src);
  if (l < 16) {
    const int k = kt_g * 16 + l;
    vout[(size_t)n * DTOT + OFF_B1 + k] = gb1v * w2r - 2.f * b1r;
    vout[(size_t)n * DTOT + OFF_W2 + k] = (gw2dot + b1r * gb1v) - 2.f * w2r;
  }
  if (kg == 0 && tid == 0) {
    float sb = 0.f;
    #pragma unroll
    for (int q = 0; q < 8; ++q) sb += Pb2[n * 8 + q];
    vout[(size_t)n * DTOT + OFF_B2] = sb - 2.f * b2[n];
  }
}

// K3: Gram partials per 128-column chunk. grid(145) x 256.
__global__ __launch_bounds__(256) void k_gram_partial(
    const float* __restrict__ W1, const float* __restrict__ b1,
    const float* __restrict__ W2, const float* __restrict__ b2,
    float* __restrict__ gpart) {
  __shared__ float ths[128][68];
  const int c0 = blockIdx.x * GCH;
  for (int idx = threadIdx.x; idx < 2048; idx += 256) {
    const int i = idx >> 5;            // 0..63
    const int dd = (idx & 31) * 4;     // 0..124
    const int d = c0 + dd;
    float v0, v1, v2, v3;
    if (d + 3 < DTOT) {
      f32x4 q;
      if (d < OFF_B1)      q = *(const f32x4*)&W1[i * 16384 + d];
      else if (d < OFF_W2) q = *(const f32x4*)&b1[i * HID + (d - OFF_B1)];
      else                 q = *(const f32x4*)&W2[i * HID + (d - OFF_W2)];
      v0 = q[0]; v1 = q[1]; v2 = q[2]; v3 = q[3];
    } else {
      v0 = (d     < DTOT) ? theta_at(i, d,     W1, b1, W2, b2) : 0.f;
      v1 = (d + 1 < DTOT) ? theta_at(i, d + 1, W1, b1, W2, b2) : 0.f;
      v2 = (d + 2 < DTOT) ? theta_at(i, d + 2, W1, b1, W2, b2) : 0.f;
      v3 = (d + 3 < DTOT) ? theta_at(i, d + 3, W1, b1, W2, b2) : 0.f;
    }
    ths[dd][i] = v0; ths[dd + 1][i] = v1; ths[dd + 2][i] = v2; ths[dd + 3][i] = v3;
  }
  __syncthreads();
  const int i0 = (threadIdx.x >> 4) << 2;
  const int j0 = (threadIdx.x & 15) << 2;
  float acc[4][4] = {};
  for (int dc = 0; dc < 128; ++dc) {
    const f32x4 av = *(const f32x4*)&ths[dc][i0];
    const f32x4 bv = *(const f32x4*)&ths[dc][j0];
    #pragma unroll
    for (int a = 0; a < 4; ++a)
      #pragma unroll
      for (int bj = 0; bj < 4; ++bj)
        acc[a][bj] = fmaf(av[a], bv[bj], acc[a][bj]);
  }
  float* __restrict__ gp = gpart + blockIdx.x * 4096;
  #pragma unroll
  for (int a = 0; a < 4; ++a)
    #pragma unroll
    for (int bj = 0; bj < 4; ++bj)
      gp[(i0 + a) * 64 + j0 + bj] = acc[a][bj];
}

// K4a: reduce Gram partials. grid(64) x 256, 4 p-slices per pair.
__global__ __launch_bounds__(256) void k_gram_reduce(
    const float* __restrict__ gpart, float* __restrict__ gram) {
  const int pl = threadIdx.x & 63;
  const int sl = threadIdx.x >> 6;
  const int pair = blockIdx.x * 64 + pl;
  float a = 0.f;
  for (int p = sl; p < NGBLK; p += 4) a += gpart[p * 4096 + pair];
  __shared__ float red[4][64];
  red[sl][pl] = a;
  __syncthreads();
  if (threadIdx.x < 64)
    gram[blockIdx.x * 64 + threadIdx.x] =
        red[0][threadIdx.x] + red[1][threadIdx.x] + red[2][threadIdx.x] + red[3][threadIdx.x];
}

// K5: out[i,d] = theta[i,d]*(1+c*s[i]) + c*sum_j kd[i,j]*V[j,d].
// kd/s computed locally from gram (k_kd folded in). grid(145) x 256.
__global__ __launch_bounds__(256) void k_update(
    const float* __restrict__ W1, const float* __restrict__ b1,
    const float* __restrict__ W2, const float* __restrict__ b2,
    const float* __restrict__ gram, float* __restrict__ vout) {
  __shared__ float Vs[64][132];
  __shared__ float kds[4096];
  __shared__ float ss[64];
  __shared__ float sq[64];
  const int c0 = blockIdx.x * GCH;
  const int cols = min(GCH, DTOT - c0);
  for (int idx = threadIdx.x; idx < 64 * GCH; idx += 256) {
    const int i = idx >> 7, dd = idx & 127;
    Vs[i][dd] = (dd < cols) ? vout[(size_t)i * DTOT + c0 + dd] : 0.f;
  }
  if (threadIdx.x < 64) sq[threadIdx.x] = gram[threadIdx.x * 65];
  __syncthreads();
  for (int q = threadIdx.x; q < 4096; q += 256) {
    const int i = q >> 6, j = q & 63;
    const float d2 = fmaxf(sq[i] + sq[j] - 2.f * gram[q], 0.f);
    kds[q] = expf(-0.5f * d2);
  }
  __syncthreads();
  if (threadIdx.x < 64) {
    float a = 0.f;
    for (int j = 0; j < 64; ++j) a += kds[threadIdx.x * 64 + j];
    ss[threadIdx.x] = a;
  }
  __syncthreads();
  const int col4 = (threadIdx.x & 31) * 4;
  const int i0 = (threadIdx.x >> 5) * 8;
  f32x4 acc[8] = {};
  for (int j = 0; j < 64; ++j) {
    const f32x4 vv = *(const f32x4*)&Vs[j][col4];
    // kd symmetric: read row j contiguously
    const f32x4 k0 = *(const f32x4*)&kds[j * 64 + i0];
    const f32x4 k1 = *(const f32x4*)&kds[j * 64 + i0 + 4];
    #pragma unroll
    for (int a = 0; a < 4; ++a) {
      acc[a][0] = fmaf(k0[a], vv[0], acc[a][0]);
      acc[a][1] = fmaf(k0[a], vv[1], acc[a][1]);
      acc[a][2] = fmaf(k0[a], vv[2], acc[a][2]);
      acc[a][3] = fmaf(k0[a], vv[3], acc[a][3]);
    }
    #pragma unroll
    for (int a = 0; a < 4; ++a) {
      acc[a + 4][0] = fmaf(k1[a], vv[0], acc[a + 4][0]);
      acc[a + 4][1] = fmaf(k1[a], vv[1], acc[a + 4][1]);
      acc[a + 4][2] = fmaf(k1[a], vv[2], acc[a + 4][2]);
      acc[a + 4][3] = fmaf(k1[a], vv[3], acc[a + 4][3]);
    }
  }
  #pragma unroll
  for (int a = 0; a < 8; ++a) {
    const int i = i0 + a;
    const float f = 1.f + STEPC * ss[i];
    #pragma unroll
    for (int cc = 0; cc < 4; ++cc) {
      const int d = c0 + col4 + cc;
      if (d < DTOT) {
        const float th = theta_at(i, d, W1, b1, W2, b2);
        vout[(size_t)i * DTOT + d] = th * f + STEPC * acc[a][cc];
      }
    }
  }
}

extern "C" void kernel_launch(void* const* d_in, const int* in_sizes, int n_in,
                              void* d_out, int out_size, void* d_ws, size_t ws_size,
                              hipStream_t stream) {
  const float* W1 = (const float*)d_in[0];
  const float* b1 = (const float*)d_in[1];
  const float* W2 = (const float*)d_in[2];
  const float* b2 = (const float*)d_in[3];
  const float* X  = (const float*)d_in[4];
  const float* y  = (const float*)d_in[5];
  float* vout = (float*)d_out;

  float* Pb2   = (float*)d_ws;            // 512 f
  float* gpart = Pb2 + 512;               // 145*4096 f
  float* gram  = gpart + NGBLK * 4096;    // 4096 f
  short* W1b   = (short*)(gram + 4096);   // 1048576 s
  short* Xb    = W1b + NP * HID * DIN;    // 32768 s
  short* XtS   = Xb + BATCH * DIN;        // 32768 s
  short* ebf   = XtS + BATCH * DIN;       // 131072 s

  k_prep<<<512, 256, 0, stream>>>(W1, X, W1b, Xb, XtS);
  k_fwd<<<dim3(NP, 8), 512, 0, stream>>>(W1b, b1, W2, b2, Xb, y, ebf, Pb2);
  k_bwd<<<dim3(NP, 8), 512, 0, stream>>>(W1, b1, W2, b2, W1b, Xb, XtS, ebf, Pb2, vout);
  k_gram_partial<<<NGBLK, 256, 0, stream>>>(W1, b1, W2, b2, gpart);
  k_gram_reduce<<<64, 256, 0, stream>>>(gpart, gram);
  k_update<<<NGBLK, 256, 0, stream>>>(W1, b1, W2, b2, gram, vout);
}